// Round 12
// baseline (86.821 us; speedup 1.0000x reference)
//
#include <hip/hip_runtime.h>
#include <hip/hip_bf16.h>
#include <stdint.h>

typedef unsigned short u16;
typedef unsigned int u32;
typedef __attribute__((ext_vector_type(8))) short bf16x8;   // 8 bf16 = 4 VGPRs
typedef __attribute__((ext_vector_type(4))) float f32x4;
typedef __attribute__((ext_vector_type(4))) unsigned short u16x4;

#define MFMA16 __builtin_amdgcn_mfma_f32_16x16x32_bf16

static constexpr int Bb = 4;
static constexpr int Cc = 256;
static constexpr int NHh = 4;
static constexpr int HDd = 64;
static constexpr int Nn = 2304;   // 48*48

__device__ __forceinline__ u16 f2bf(float f) {
  u32 u = __builtin_bit_cast(u32, f);
  u32 r = u + 0x7fffu + ((u >> 16) & 1u);   // RNE
  return (u16)(r >> 16);
}

__device__ __forceinline__ u32 cvtpk(float a, float b) {  // lo=bf16(a), hi=bf16(b)
  u32 r;
  asm("v_cvt_pk_bf16_f32 %0, %1, %2" : "=v"(r) : "v"(a), "v"(b));
  return r;
}

__device__ __forceinline__ float blo(u32 u) { return __builtin_bit_cast(float, u << 16); }
__device__ __forceinline__ float bhi(u32 u) { return __builtin_bit_cast(float, u & 0xffff0000u); }

__device__ __forceinline__ void async16(const void* g, void* l) {
  __builtin_amdgcn_global_load_lds(
      (const __attribute__((address_space(1))) u32*)g,
      (__attribute__((address_space(3))) u32*)l, 16, 0, 0);
}

// ---------------- kernel 1: weight cast only ----------------
__global__ __launch_bounds__(256) void k_prep(const float* __restrict__ wq,
                                              const float* __restrict__ wp,
                                              u16* __restrict__ wqb,
                                              u16* __restrict__ wpb) {
  int i = blockIdx.x * 256 + threadIdx.x;
  if (i < 3 * Cc * Cc) wqb[i] = f2bf(wq[i]);
  if (i < Cc * Cc)     wpb[i] = f2bf(wp[i]);
}

// ---------------- kernel 2: QKV GEMM with fused x-transpose ----------------
// Stages B-tile [64 n][256 c] bf16 (swizzled) directly from x[b][c][n] f32
// via in-LDS transpose (4 chunks of 64c x 64n).  o-tile 128 (2 passes).
__global__ __launch_bounds__(256) void k_qkv(const u16* __restrict__ wqb,
                                             const float* __restrict__ x,
                                             const float* __restrict__ bqkv,
                                             u16* __restrict__ qT, u16* __restrict__ kT,
                                             u16* __restrict__ vT) {
  __shared__ float tile[64][65];
  __shared__ u16 Bs[64 * 256];   // [n-row][c], rows XOR-swizzled in 16B units
  int n0 = blockIdx.y * 64, b = blockIdx.z;
  int t = threadIdx.x, w = t >> 6, l = t & 63, g = l >> 4, li = l & 15;
  char* BsB = (char*)Bs;
#pragma unroll
  for (int cc = 0; cc < 4; ++cc) {
    // load 64 c-rows x 64 n-cols f32, coalesced along n
#pragma unroll
    for (int i = 0; i < 16; ++i) {
      int cl = i * 4 + w;
      tile[cl][l] = x[((size_t)(b * Cc + cc * 64 + cl)) * Nn + n0 + l];
    }
    __syncthreads();
    // write transposed bf16 into Bs (swizzled rows)
#pragma unroll
    for (int i = 0; i < 16; ++i) {
      int nr = i * 4 + w;
      int byte = nr * 512 + ((2 * (cc * 64 + l)) ^ ((nr & 7) << 4));
      *(u16*)(BsB + byte) = f2bf(tile[l][nr]);
    }
    __syncthreads();
  }
  const float qs = 0.0625f * 1.44269504088896340736f;
#pragma unroll
  for (int p = 0; p < 2; ++p) {
    int o0 = blockIdx.x * 128 + p * 64;
    const u16* Arow = wqb + (size_t)(o0 + w * 16 + li) * Cc;
    f32x4 acc[4] = {};
#pragma unroll
    for (int s = 0; s < 8; ++s) {
      bf16x8 a = *(const bf16x8*)(Arow + s * 32 + g * 8);
#pragma unroll
      for (int nt = 0; nt < 4; ++nt) {
        int row = nt * 16 + li;
        const char* bp_ = (const char*)Bs + row * 512 + ((s * 64 + g * 16) ^ ((row & 7) << 4));
        bf16x8 bb = *(const bf16x8*)bp_;
        acc[nt] = MFMA16(a, bb, acc[nt], 0, 0, 0);
      }
    }
    int which = o0 >> 8;              // wg-uniform: 0=q 1=k 2=v
    int hh = (o0 >> 6) & 3;
    int bh = b * NHh + hh;
    int dbase = w * 16 + g * 4;
#pragma unroll
    for (int nt = 0; nt < 4; ++nt) {
      int n = n0 + nt * 16 + li;
      float v0 = acc[nt][0] + bqkv[o0 + dbase + 0];
      float v1 = acc[nt][1] + bqkv[o0 + dbase + 1];
      float v2 = acc[nt][2] + bqkv[o0 + dbase + 2];
      float v3 = acc[nt][3] + bqkv[o0 + dbase + 3];
      if (which == 0) {
        u16x4 pq = {f2bf(v0 * qs), f2bf(v1 * qs), f2bf(v2 * qs), f2bf(v3 * qs)};
        *(u16x4*)(qT + ((size_t)bh * Nn + n) * HDd + dbase) = pq;
      } else if (which == 1) {
        u16x4 pk = {f2bf(v0), f2bf(v1), f2bf(v2), f2bf(v3)};
        *(u16x4*)(kT + ((size_t)bh * Nn + n) * HDd + dbase) = pk;
      } else {
        vT[((size_t)bh * HDd + dbase + 0) * Nn + n] = f2bf(v0);
        vT[((size_t)bh * HDd + dbase + 1) * Nn + n] = f2bf(v1);
        vT[((size_t)bh * HDd + dbase + 2) * Nn + n] = f2bf(v2);
        vT[((size_t)bh * HDd + dbase + 3) * Nn + n] = f2bf(v3);
      }
    }
  }
}

// ---------------- kernel 3: flash attention (BIT-IDENTICAL r11 core) ----------------
__global__ __launch_bounds__(192) void k_attn(const u16* __restrict__ qT,
                                              const u16* __restrict__ kT,
                                              const u16* __restrict__ vT,
                                              u16* __restrict__ attP,
                                              float* __restrict__ lsumP) {
  __shared__ u16 Ks[2][32 * 64];   // [buf][key][d]   swizzled (128B rows)  8 KB
  __shared__ u16 Vs[2][64 * 32];   // [buf][d][key]   swizzled (64B rows)   8 KB
  __shared__ u16 Ps[3][32 * 32];   // per-wave P [q:32][key:32] swizzled    6 KB
  int L = blockIdx.x;
  int xcd = L & 7, r = L >> 3;            // r in 0..191
  int bh = 2 * xcd + (r >= 96 ? 1 : 0);
  int r2 = (r >= 96) ? r - 96 : r;        // 0..95
  int quarter = r2 / 24;                  // 0..3
  int qb = r2 % 24;                       // 0..23
  int t = threadIdx.x, w = t / 64, l = t & 63, g = l >> 4, li = l & 15;
  int q0 = qb * 96 + w * 32;
  const u16* qr0 = qT + ((size_t)bh * Nn + q0 + li) * HDd;
  const u16* qr1 = qT + ((size_t)bh * Nn + q0 + 16 + li) * HDd;
  bf16x8 bq[2][2];
  bq[0][0] = *(const bf16x8*)(qr0 + g * 8);
  bq[0][1] = *(const bf16x8*)(qr0 + 32 + g * 8);
  bq[1][0] = *(const bf16x8*)(qr1 + g * 8);
  bq[1][1] = *(const bf16x8*)(qr1 + 32 + g * 8);
  const short one = (short)0x3F80;         // bf16 1.0
  bf16x8 ONES = {one, one, one, one, one, one, one, one};
  f32x4 acc[2][4] = {};                    // [set][dt]
  f32x4 acc_l[2] = {};                     // [set]
  const char* kbh = (const char*)(kT + (size_t)bh * Nn * HDd);
  const char* vbh = (const char*)(vT + (size_t)bh * HDd * Nn);
  char* PsB = (char*)(&Ps[w][0]);
  int sw_li = (li & 7) << 4;               // K read swizzle (128B rows)
  int sw2   = ((li >> 1) & 3) << 4;        // V / Ps swizzle (64B rows, 2-way max)

  const char* sp[3];
  int sd[3];
  ptrdiff_t sstr[3];
  bool son[3], svv[3];
#pragma unroll
  for (int it = 0; it < 3; ++it) {
    int gg = w * 3 + it;
    son[it] = (gg < 8);
    int c = gg * 64 + l;
    if (c < 256) {                 // K chunk: key=c>>3 (0..31), c8=c&7
      int key = c >> 3, c8 = c & 7;
      sp[it] = kbh + (size_t)(quarter * 576 + key) * 128 + ((c8 * 16) ^ ((key & 7) << 4));
      sd[it] = c * 16; sstr[it] = 32 * 128; svv[it] = false;
    } else {                       // V chunk: d=cv>>2 (0..63), c4=cv&3
      int cv = c - 256, d = cv >> 2, c4 = cv & 3;
      sp[it] = vbh + (size_t)d * (Nn * 2) + quarter * 1152 +
               ((c4 * 16) ^ (((d >> 1) & 3) << 4));
      sd[it] = cv * 16; sstr[it] = 32 * 2; svv[it] = true;
    }
  }

  auto STAGE = [&](int buf) {
    char* kdst = (char*)(&Ks[0][0]) + buf * 4096;
    char* vdst = (char*)(&Vs[0][0]) + buf * 4096;
#pragma unroll
    for (int it = 0; it < 3; ++it) {
      if (son[it]) {
        async16(sp[it], (svv[it] ? vdst : kdst) + sd[it]);
        sp[it] += sstr[it];
      }
    }
  };

  STAGE(0);
  int cur = 0;
  for (int kb = 0; kb < 18; ++kb) {
    __syncthreads();
    if (kb + 1 < 18) STAGE(cur ^ 1);

    const char* Kc = (const char*)(&Ks[0][0]) + cur * 4096;
    const char* Vc = (const char*)(&Vs[0][0]) + cur * 4096;

    f32x4 s[2][2];                          // [set][kt]
    __builtin_amdgcn_s_setprio(1);
#pragma unroll
    for (int kt = 0; kt < 2; ++kt) {
      const char* kr = Kc + (kt * 16 + li) * 128;
      bf16x8 a0 = *(const bf16x8*)(kr + ((g * 16) ^ sw_li));
      bf16x8 a1 = *(const bf16x8*)(kr + ((64 + g * 16) ^ sw_li));
#pragma unroll
      for (int st = 0; st < 2; ++st) {
        f32x4 z = {};
        z = MFMA16(a0, bq[st][0], z, 0, 0, 0);
        z = MFMA16(a1, bq[st][1], z, 0, 0, 0);
        s[st][kt] = z;
      }
    }
    __builtin_amdgcn_s_setprio(0);

#pragma unroll
    for (int st = 0; st < 2; ++st) {
#pragma unroll
      for (int kt = 0; kt < 2; ++kt)
#pragma unroll
        for (int j = 0; j < 4; ++j) s[st][kt][j] = exp2f(s[st][kt][j]);
      int rq = st * 16 + li;
#pragma unroll
      for (int kt = 0; kt < 2; ++kt) {
        uint2 pk;
        pk.x = cvtpk(s[st][kt][0], s[st][kt][1]);
        pk.y = cvtpk(s[st][kt][2], s[st][kt][3]);
        *(uint2*)(PsB + rq * 64 + ((kt * 32 + g * 8) ^ sw2)) = pk;
      }
    }
    bf16x8 pa[2];
    pa[0] = *(const bf16x8*)(PsB + (0 * 16 + li) * 64 + ((g * 16) ^ sw2));
    pa[1] = *(const bf16x8*)(PsB + (1 * 16 + li) * 64 + ((g * 16) ^ sw2));
    __builtin_amdgcn_s_setprio(1);
    acc_l[0] = MFMA16(pa[0], ONES, acc_l[0], 0, 0, 0);
    acc_l[1] = MFMA16(pa[1], ONES, acc_l[1], 0, 0, 0);
#pragma unroll
    for (int dt = 0; dt < 4; ++dt) {
      const char* vr = Vc + (dt * 16 + li) * 64;
      bf16x8 v0 = *(const bf16x8*)(vr + ((g * 16) ^ sw2));
      acc[0][dt] = MFMA16(pa[0], v0, acc[0][dt], 0, 0, 0);
      acc[1][dt] = MFMA16(pa[1], v0, acc[1][dt], 0, 0, 0);
    }
    __builtin_amdgcn_s_setprio(0);
    cur ^= 1;
  }
  u16* ap = attP + (size_t)quarter * (Bb * Nn * Cc);
  float* lp = lsumP + quarter * (Bb * NHh * Nn);
  if (li == 0) {
#pragma unroll
    for (int st = 0; st < 2; ++st)
#pragma unroll
      for (int j = 0; j < 4; ++j)
        lp[bh * Nn + q0 + st * 16 + g * 4 + j] = acc_l[st][j];
  }
  int b = bh >> 2, hh = bh & 3;
#pragma unroll
  for (int st = 0; st < 2; ++st)
#pragma unroll
    for (int dt = 0; dt < 4; ++dt) {
      int cidx = hh * 64 + dt * 16 + li;
#pragma unroll
      for (int j = 0; j < 4; ++j) {
        ap[((size_t)(b * Nn + q0 + st * 16 + g * 4 + j)) * Cc + cidx] = f2bf(acc[st][dt][j]);
      }
    }
}

// ---------------- kernel 4: 4-way merge + normalize -> attT bf16 ----------------
__global__ __launch_bounds__(256) void k_merge(const u16* __restrict__ attP,
                                               const float* __restrict__ lsumP,
                                               u16* __restrict__ attT) {
  int gid = blockIdx.x * 256 + threadIdx.x;     // 294912 threads, 8 elems each
  int base = gid * 8;
  int bidx = base / (Nn * Cc);
  int rem = base - bidx * (Nn * Cc);
  int n = rem >> 8, c = rem & 255;
  int hh = c >> 6;
  int lidx = (bidx * NHh + hh) * Nn + n;
  const int LQ = Bb * NHh * Nn;
  float inv = 1.0f / (lsumP[lidx] + lsumP[LQ + lidx] +
                      lsumP[2 * LQ + lidx] + lsumP[3 * LQ + lidx]);
  const size_t QSZ = (size_t)Bb * Nn * Cc;
  uint4 p0 = *(const uint4*)(attP + base);
  uint4 p1 = *(const uint4*)(attP + QSZ + base);
  uint4 p2 = *(const uint4*)(attP + 2 * QSZ + base);
  uint4 p3 = *(const uint4*)(attP + 3 * QSZ + base);
  uint4 o;
  o.x = cvtpk((blo(p0.x) + blo(p1.x) + blo(p2.x) + blo(p3.x)) * inv,
              (bhi(p0.x) + bhi(p1.x) + bhi(p2.x) + bhi(p3.x)) * inv);
  o.y = cvtpk((blo(p0.y) + blo(p1.y) + blo(p2.y) + blo(p3.y)) * inv,
              (bhi(p0.y) + bhi(p1.y) + bhi(p2.y) + bhi(p3.y)) * inv);
  o.z = cvtpk((blo(p0.z) + blo(p1.z) + blo(p2.z) + blo(p3.z)) * inv,
              (bhi(p0.z) + bhi(p1.z) + bhi(p2.z) + bhi(p3.z)) * inv);
  o.w = cvtpk((blo(p0.w) + blo(p1.w) + blo(p2.w) + blo(p3.w)) * inv,
              (bhi(p0.w) + bhi(p1.w) + bhi(p2.w) + bhi(p3.w)) * inv);
  *(uint4*)(attT + base) = o;
}

// ---------------- kernel 5: proj GEMM (o-tile 128) -> fp32 out ----------------
__global__ __launch_bounds__(256) void k_proj(const u16* __restrict__ wpb,
                                              const u16* __restrict__ attT,
                                              const float* __restrict__ bp,
                                              float* __restrict__ out) {
  __shared__ u16 Bs[32 * 256];      // [n-row][c], swizzled rows  16 KB
  int bx = blockIdx.x, n0 = blockIdx.y * 32, b = blockIdx.z;
  int t = threadIdx.x, w = t >> 6, l = t & 63, g = l >> 4, li = l & 15;
#pragma unroll
  for (int it = 0; it < 4; ++it) {
    int ch = it * 256 + t;           // 0..1023 chunks of 16B
    int row = ch >> 5, c16 = ch & 31;
    const char* src = (const char*)attT + ((size_t)(b * Nn + n0 + row)) * 512 +
                      ((c16 * 16) ^ ((row & 7) << 4));
    async16(src, (char*)Bs + (it * 256 + (t & ~63)) * 16);
  }
  const u16* Arow0 = wpb + (size_t)(bx * 128 + w * 16 + li) * Cc;
  const u16* Arow1 = Arow0 + (size_t)64 * Cc;
  __syncthreads();
  f32x4 acc[2][2] = {};              // [p][nt]
#pragma unroll
  for (int s = 0; s < 8; ++s) {
    bf16x8 a0 = *(const bf16x8*)(Arow0 + s * 32 + g * 8);
    bf16x8 a1 = *(const bf16x8*)(Arow1 + s * 32 + g * 8);
#pragma unroll
    for (int nt = 0; nt < 2; ++nt) {
      int row = nt * 16 + li;
      const char* bp_ = (const char*)Bs + row * 512 + ((s * 64 + g * 16) ^ ((row & 7) << 4));
      bf16x8 bb = *(const bf16x8*)bp_;
      acc[0][nt] = MFMA16(a0, bb, acc[0][nt], 0, 0, 0);
      acc[1][nt] = MFMA16(a1, bb, acc[1][nt], 0, 0, 0);
    }
  }
#pragma unroll
  for (int nt = 0; nt < 2; ++nt) {
    int n = n0 + nt * 16 + li;
#pragma unroll
    for (int p = 0; p < 2; ++p) {
      int obase = bx * 128 + p * 64 + w * 16 + g * 4;
#pragma unroll
      for (int j = 0; j < 4; ++j) {
        out[((size_t)(b * Cc + obase + j)) * Nn + n] = acc[p][nt][j] + bp[obase + j];
      }
    }
  }
}

extern "C" void kernel_launch(void* const* d_in, const int* in_sizes, int n_in,
                              void* d_out, int out_size, void* d_ws, size_t ws_size,
                              hipStream_t stream) {
  const float* x     = (const float*)d_in[0];
  const float* wqkv  = (const float*)d_in[1];
  const float* bqkv  = (const float*)d_in[2];
  const float* wproj = (const float*)d_in[3];
  const float* bproj = (const float*)d_in[4];
  float* out = (float*)d_out;

  u16* ws    = (u16*)d_ws;
  u16* wq_bf = ws;                     // 196608
  u16* wp_bf = wq_bf + 196608;         // 65536
  u16* qT    = wp_bf + 65536;          // 2359296
  u16* kT    = qT + 2359296;           // 2359296
  u16* vT    = kT + 2359296;           // 2359296
  u16* attP  = vT + 2359296;           // 4 x 2359296 bf16 quarter partials
  float* lsumP = (float*)(attP + 4 * 2359296);   // 4 x 36864 f32
  u16* attT  = qT;                     // overlays qT (dead after k_attn)

  k_prep<<<dim3(768), dim3(256), 0, stream>>>(wqkv, wproj, wq_bf, wp_bf);
  k_qkv<<<dim3(6, 36, 4), dim3(256), 0, stream>>>(wq_bf, x, bqkv, qT, kT, vT);
  k_attn<<<dim3(1536), dim3(192), 0, stream>>>(qT, kT, vT, attP, lsumP);
  k_merge<<<dim3(1152), dim3(256), 0, stream>>>(attP, lsumP, attT);
  k_proj<<<dim3(2, 72, 4), dim3(256), 0, stream>>>(wp_bf, attT, bproj, out);
}